// Round 1
// baseline (511.454 us; speedup 1.0000x reference)
//
#include <hip/hip_runtime.h>
#include <math.h>

#define BB 32
#define PP 32768
#define OO 50
#define NC 21

typedef unsigned long long u64;
typedef unsigned int u32;
typedef unsigned char u8;

// workspace layout
static constexpr size_t OFF_KEYS  = 0;                          // u64[BB*OO]
static constexpr size_t OFF_BTOV  = 16384;                      // float[BB*PP]
static constexpr size_t OFF_BTIDX = OFF_BTOV  + 4ull*BB*PP;     // u8[BB*PP]
static constexpr size_t OFF_CEM   = OFF_BTIDX + 1ull*BB*PP;     // float[BB*PP]
static constexpr size_t OFF_NPOS  = OFF_CEM   + 4ull*BB*PP;     // int[BB]
static constexpr size_t OFF_DACC  = OFF_NPOS  + 128;            // double[3*BB]: lossl, posce, topk

__global__ void init_kernel(u64* __restrict__ keys, int* __restrict__ npos,
                            double* __restrict__ dacc) {
    int i = blockIdx.x * 256 + threadIdx.x;
    if (i < BB * OO) keys[i] = 0ull;
    if (i < BB) npos[i] = 0;
    if (i < 3 * BB) dacc[i] = 0.0;
}

// Per (b,p): IoU against all 50 truths. Tracks per-prior best truth (first max)
// and per-truth best prior via packed u64 atomicMax (value_bits<<32 | ~p ->
// max value, ties prefer smaller p == numpy argmax first-occurrence).
__global__ __launch_bounds__(256) void match_kernel(
    const float* __restrict__ priors, const float* __restrict__ targets,
    float* __restrict__ btov, u8* __restrict__ btidx, u64* __restrict__ keys)
{
#pragma clang fp contract(off)
    const int b = blockIdx.y;
    const int p = blockIdx.x * 256 + threadIdx.x;
    const int tid = threadIdx.x;
    __shared__ float tr[OO * 5];
    __shared__ u64 wkeys[4][OO];
    if (tid < OO * 5) tr[tid] = targets[(size_t)b * OO * 5 + tid];
    __syncthreads();

    float4 pr = *(const float4*)(priors + (size_t)p * 4);
    float px1 = pr.x - pr.z * 0.5f, py1 = pr.y - pr.w * 0.5f;
    float px2 = pr.x + pr.z * 0.5f, py2 = pr.y + pr.w * 0.5f;
    float area_p = (px2 - px1) * (py2 - py1);

    float bestv = -1.0f; int besto = 0;
    const int lane = tid & 63, wid = tid >> 6;
    for (int o = 0; o < OO; ++o) {
        float tx1 = tr[o*5+0], ty1 = tr[o*5+1], tx2 = tr[o*5+2], ty2 = tr[o*5+3];
        float ix1 = fmaxf(tx1, px1), iy1 = fmaxf(ty1, py1);
        float ix2 = fminf(tx2, px2), iy2 = fminf(ty2, py2);
        float dx = fmaxf(ix2 - ix1, 0.0f), dy = fmaxf(iy2 - iy1, 0.0f);
        float inter = dx * dy;
        float area_t = (tx2 - tx1) * (ty2 - ty1);
        float iou = inter / ((area_t + area_p) - inter);
        if (iou > bestv) { bestv = iou; besto = o; }   // strict >: first max over o

        u64 key = ((u64)__float_as_uint(iou) << 32) | (u64)(0xFFFFFFFFu - (u32)p);
        for (int m = 1; m < 64; m <<= 1) {
            u64 other = __shfl_xor(key, m, 64);
            if (other > key) key = other;
        }
        if (lane == 0) wkeys[wid][o] = key;
    }
    btov[(size_t)b * PP + p] = bestv;
    btidx[(size_t)b * PP + p] = (u8)besto;
    __syncthreads();
    if (tid < OO) {
        u64 k0 = wkeys[0][tid];
        for (int w = 1; w < 4; ++w) { u64 kw = wkeys[w][tid]; if (kw > k0) k0 = kw; }
        atomicMax(&keys[b * OO + tid], k0);
    }
}

// Sequential per batch (last-wins scatter, matches numpy fancy assignment).
__global__ void override_kernel(const u64* __restrict__ keys,
                                float* __restrict__ btov, u8* __restrict__ btidx) {
    int b = threadIdx.x;
    if (b >= BB) return;
    for (int o = 0; o < OO; ++o) {
        u64 key = keys[b * OO + o];
        u32 p = 0xFFFFFFFFu - (u32)(key & 0xFFFFFFFFull);
        btov[(size_t)b * PP + p] = 2.0f;
        btidx[(size_t)b * PP + p] = (u8)o;
    }
}

__global__ __launch_bounds__(256) void score_kernel(
    const float* __restrict__ loc, const float* __restrict__ conf,
    const float* __restrict__ priors, const float* __restrict__ targets,
    const float* __restrict__ btov, const u8* __restrict__ btidx,
    float* __restrict__ cemine, int* __restrict__ npos, double* __restrict__ dacc)
{
    const int b = blockIdx.y;
    const int p = blockIdx.x * 256 + threadIdx.x;
    const int tid = threadIdx.x;
    __shared__ float tr[OO * 5];
    if (tid < OO * 5) tr[tid] = targets[(size_t)b * OO * 5 + tid];
    __syncthreads();

    float ov = btov[(size_t)b * PP + p];
    int o = btidx[(size_t)b * PP + p];
    int conft = 0;
    if (ov >= 0.5f) conft = (int)(tr[o*5+4] + 1.0f);
    bool pos = conft > 0;

    const float* cr = conf + ((size_t)b * PP + p) * NC;
    float x[NC];
    float m = -1e30f;
#pragma unroll
    for (int c = 0; c < NC; ++c) { x[c] = cr[c]; m = fmaxf(m, x[c]); }
    float s = 0.0f, tl = 0.0f;
#pragma unroll
    for (int c = 0; c < NC; ++c) { s += expf(x[c] - m); if (c == conft) tl = x[c]; }
    float ce = (m + logf(s)) - tl;

    cemine[(size_t)b * PP + p] = pos ? 0.0f : ce;

    double l_l = 0.0, pce = 0.0; int np_ = 0;
    if (pos) {
        np_ = 1; pce = (double)ce;
        float mx1 = tr[o*5+0], my1 = tr[o*5+1], mx2 = tr[o*5+2], my2 = tr[o*5+3];
        float4 pr = *(const float4*)(priors + (size_t)p * 4);
        float lt0 = ((mx1 + mx2) * 0.5f - pr.x) / (0.1f * pr.z);
        float lt1 = ((my1 + my2) * 0.5f - pr.y) / (0.1f * pr.w);
        float lt2 = logf((mx2 - mx1) / pr.z) / 0.2f;
        float lt3 = logf((my2 - my1) / pr.w) / 0.2f;
        const float* lp = loc + ((size_t)b * PP + p) * 4;
        float lt[4] = {lt0, lt1, lt2, lt3};
#pragma unroll
        for (int i2 = 0; i2 < 4; ++i2) {
            float d = lp[i2] - lt[i2];
            float ad = fabsf(d);
            l_l += (double)(ad < 1.0f ? 0.5f * d * d : ad - 0.5f);
        }
    }

    __shared__ double rl[256], rc[256];
    __shared__ int rn[256];
    rl[tid] = l_l; rc[tid] = pce; rn[tid] = np_;
    __syncthreads();
    for (int s2 = 128; s2 > 0; s2 >>= 1) {
        if (tid < s2) { rl[tid] += rl[tid+s2]; rc[tid] += rc[tid+s2]; rn[tid] += rn[tid+s2]; }
        __syncthreads();
    }
    if (tid == 0) {
        atomicAdd(&dacc[b], rl[0]);
        atomicAdd(&dacc[BB + b], rc[0]);
        atomicAdd(&npos[b], rn[0]);
    }
}

// Exact top-k sum of ce_mine per batch via 3-pass radix select on u32 bits
// (values >= 0, bit pattern order == float order). Sum of top-k multiset is
// tie-independent, so this equals the argsort-based reference selection sum.
__global__ __launch_bounds__(256) void topk_kernel(
    const float* __restrict__ cemine, const int* __restrict__ npos,
    double* __restrict__ dacc)
{
    const int b = blockIdx.x, tid = threadIdx.x;
    const float* v = cemine + (size_t)b * PP;
    int k = npos[b] * 3; if (k > PP - 1) k = PP - 1;
    if (k <= 0) { if (tid == 0) dacc[2*BB + b] = 0.0; return; }

    __shared__ u32 hist[2048];
    __shared__ u32 s_pre; __shared__ int s_k;

    // pass 1: bits [31:21]
    for (int i = tid; i < 2048; i += 256) hist[i] = 0;
    __syncthreads();
    for (int i = tid; i < PP; i += 256) {
        u32 u = __float_as_uint(fmaxf(v[i], 0.0f));
        atomicAdd(&hist[u >> 21], 1u);
    }
    __syncthreads();
    if (tid == 0) {
        int cum = 0, bin = 2047;
        for (;; --bin) { cum += (int)hist[bin]; if (cum >= k || bin == 0) break; }
        s_pre = (u32)bin; s_k = k - (cum - (int)hist[bin]);
    }
    __syncthreads();
    u32 pre1 = s_pre; int k2 = s_k;
    __syncthreads();

    // pass 2: bits [20:10] within prefix
    for (int i = tid; i < 2048; i += 256) hist[i] = 0;
    __syncthreads();
    for (int i = tid; i < PP; i += 256) {
        u32 u = __float_as_uint(fmaxf(v[i], 0.0f));
        if ((u >> 21) == pre1) atomicAdd(&hist[(u >> 10) & 2047u], 1u);
    }
    __syncthreads();
    if (tid == 0) {
        int cum = 0, bin = 2047;
        for (;; --bin) { cum += (int)hist[bin]; if (cum >= k2 || bin == 0) break; }
        s_pre = (pre1 << 11) | (u32)bin; s_k = k2 - (cum - (int)hist[bin]);
    }
    __syncthreads();
    u32 pre2 = s_pre; int k3 = s_k;
    __syncthreads();

    // pass 3: bits [9:0] within prefix
    for (int i = tid; i < 2048; i += 256) hist[i] = 0;
    __syncthreads();
    for (int i = tid; i < PP; i += 256) {
        u32 u = __float_as_uint(fmaxf(v[i], 0.0f));
        if ((u >> 10) == pre2) atomicAdd(&hist[u & 1023u], 1u);
    }
    __syncthreads();
    if (tid == 0) {
        int cum = 0, bin = 1023;
        for (;; --bin) { cum += (int)hist[bin]; if (cum >= k3 || bin == 0) break; }
        s_pre = (pre2 << 10) | (u32)bin; s_k = k3 - (cum - (int)hist[bin]); // # equal to T to take
    }
    __syncthreads();
    u32 T = s_pre; int teq = s_k;

    // sum pass: sum of values strictly greater than T, plus teq * T
    double acc = 0.0;
    for (int i = tid; i < PP; i += 256) {
        u32 u = __float_as_uint(fmaxf(v[i], 0.0f));
        if (u > T) acc += (double)v[i];
    }
    __shared__ double red[256];
    red[tid] = acc;
    __syncthreads();
    for (int s2 = 128; s2 > 0; s2 >>= 1) {
        if (tid < s2) red[tid] += red[tid + s2];
        __syncthreads();
    }
    if (tid == 0) dacc[2*BB + b] = red[0] + (double)teq * (double)__uint_as_float(T);
}

__global__ void finalize_kernel(const int* __restrict__ npos,
                                const double* __restrict__ dacc, float* __restrict__ out) {
    if (threadIdx.x == 0 && blockIdx.x == 0) {
        double N = 0.0, ll = 0.0, lc = 0.0;
        for (int b = 0; b < BB; ++b) {
            N += (double)npos[b];
            ll += dacc[b];
            lc += dacc[BB + b] + dacc[2*BB + b];
        }
        out[0] = (float)(ll / N);
        out[1] = (float)(lc / N);
    }
}

extern "C" void kernel_launch(void* const* d_in, const int* in_sizes, int n_in,
                              void* d_out, int out_size, void* d_ws, size_t ws_size,
                              hipStream_t stream) {
    const float* loc     = (const float*)d_in[0];
    const float* conf    = (const float*)d_in[1];
    const float* priors  = (const float*)d_in[2];
    const float* targets = (const float*)d_in[3];
    char* ws = (char*)d_ws;
    u64*    keys  = (u64*)   (ws + OFF_KEYS);
    float*  btov  = (float*) (ws + OFF_BTOV);
    u8*     btidx = (u8*)    (ws + OFF_BTIDX);
    float*  cem   = (float*) (ws + OFF_CEM);
    int*    npos  = (int*)   (ws + OFF_NPOS);
    double* dacc  = (double*)(ws + OFF_DACC);
    float*  out   = (float*)d_out;

    init_kernel<<<7, 256, 0, stream>>>(keys, npos, dacc);
    dim3 g1(PP / 256, BB);
    match_kernel<<<g1, 256, 0, stream>>>(priors, targets, btov, btidx, keys);
    override_kernel<<<1, 32, 0, stream>>>(keys, btov, btidx);
    score_kernel<<<g1, 256, 0, stream>>>(loc, conf, priors, targets, btov, btidx, cem, npos, dacc);
    topk_kernel<<<BB, 256, 0, stream>>>(cem, npos, dacc);
    finalize_kernel<<<1, 64, 0, stream>>>(npos, dacc, out);
}

// Round 2
// 329.453 us; speedup vs baseline: 1.5524x; 1.5524x over previous
//
#include <hip/hip_runtime.h>
#include <math.h>

#define BB 32
#define PP 32768
#define OO 50
#define NC 21
#define NBIN 65536

typedef unsigned long long u64;
typedef unsigned int u32;
typedef unsigned char u8;

// workspace layout (all offsets 128B-aligned)
static constexpr size_t OFF_KEYS  = 0;                           // u64[BB*OO]
static constexpr size_t OFF_BTOV  = 16384;                       // float[BB*PP]
static constexpr size_t OFF_BTIDX = OFF_BTOV  + 4ull*BB*PP;      // u8[BB*PP]
static constexpr size_t OFF_CEM   = OFF_BTIDX + 1ull*BB*PP;      // float[BB*PP]
static constexpr size_t OFF_NPOS  = OFF_CEM   + 4ull*BB*PP;      // int[BB]
static constexpr size_t OFF_SELT  = OFF_NPOS  + 128;             // u32[BB] threshold top16 bin
static constexpr size_t OFF_SELK  = OFF_SELT  + 128;             // int[BB] residual k within bin
static constexpr size_t OFF_DACC  = OFF_SELK  + 128;             // double[3*BB]: lossl, posce, topk
static constexpr size_t OFF_HIST  = OFF_DACC  + 8ull*3*BB + 64;  // u32[BB*NBIN]
static constexpr size_t OFF_HIST2 = OFF_HIST  + 4ull*BB*NBIN;    // u32[BB*NBIN]

__global__ void init_kernel(u64* __restrict__ keys, int* __restrict__ npos,
                            double* __restrict__ dacc) {
    int i = blockIdx.x * 256 + threadIdx.x;
    if (i < BB * OO) keys[i] = 0ull;
    if (i < BB) npos[i] = 0;
    if (i < 3 * BB) dacc[i] = 0.0;
}

// Per (b,p): IoU against all 50 truths. Tracks per-prior best truth (first max)
// and per-truth best prior via packed u64 atomicMax (value_bits<<32 | ~p ->
// max value, ties prefer smaller p == numpy argmax first-occurrence).
__global__ __launch_bounds__(256) void match_kernel(
    const float* __restrict__ priors, const float* __restrict__ targets,
    float* __restrict__ btov, u8* __restrict__ btidx, u64* __restrict__ keys)
{
#pragma clang fp contract(off)
    const int b = blockIdx.y;
    const int p = blockIdx.x * 256 + threadIdx.x;
    const int tid = threadIdx.x;
    __shared__ float tr[OO * 5];
    __shared__ u64 wkeys[4][OO];
    if (tid < OO * 5) tr[tid] = targets[(size_t)b * OO * 5 + tid];
    __syncthreads();

    float4 pr = *(const float4*)(priors + (size_t)p * 4);
    float px1 = pr.x - pr.z * 0.5f, py1 = pr.y - pr.w * 0.5f;
    float px2 = pr.x + pr.z * 0.5f, py2 = pr.y + pr.w * 0.5f;
    float area_p = (px2 - px1) * (py2 - py1);

    float bestv = -1.0f; int besto = 0;
    const int lane = tid & 63, wid = tid >> 6;
    for (int o = 0; o < OO; ++o) {
        float tx1 = tr[o*5+0], ty1 = tr[o*5+1], tx2 = tr[o*5+2], ty2 = tr[o*5+3];
        float ix1 = fmaxf(tx1, px1), iy1 = fmaxf(ty1, py1);
        float ix2 = fminf(tx2, px2), iy2 = fminf(ty2, py2);
        float dx = fmaxf(ix2 - ix1, 0.0f), dy = fmaxf(iy2 - iy1, 0.0f);
        float inter = dx * dy;
        float area_t = (tx2 - tx1) * (ty2 - ty1);
        float iou = inter / ((area_t + area_p) - inter);
        if (iou > bestv) { bestv = iou; besto = o; }   // strict >: first max over o

        u64 key = ((u64)__float_as_uint(iou) << 32) | (u64)(0xFFFFFFFFu - (u32)p);
        for (int m = 1; m < 64; m <<= 1) {
            u64 other = __shfl_xor(key, m, 64);
            if (other > key) key = other;
        }
        if (lane == 0) wkeys[wid][o] = key;
    }
    btov[(size_t)b * PP + p] = bestv;
    btidx[(size_t)b * PP + p] = (u8)besto;
    __syncthreads();
    if (tid < OO) {
        u64 k0 = wkeys[0][tid];
        for (int w = 1; w < 4; ++w) { u64 kw = wkeys[w][tid]; if (kw > k0) k0 = kw; }
        atomicMax(&keys[b * OO + tid], k0);
    }
}

// Sequential per batch (last-wins scatter, matches numpy fancy assignment).
__global__ void override_kernel(const u64* __restrict__ keys,
                                float* __restrict__ btov, u8* __restrict__ btidx) {
    int b = threadIdx.x;
    if (b >= BB) return;
    for (int o = 0; o < OO; ++o) {
        u64 key = keys[b * OO + o];
        u32 p = 0xFFFFFFFFu - (u32)(key & 0xFFFFFFFFull);
        btov[(size_t)b * PP + p] = 2.0f;
        btidx[(size_t)b * PP + p] = (u8)o;
    }
}

__global__ __launch_bounds__(256) void score_kernel(
    const float* __restrict__ loc, const float* __restrict__ conf,
    const float* __restrict__ priors, const float* __restrict__ targets,
    const float* __restrict__ btov, const u8* __restrict__ btidx,
    float* __restrict__ cemine, int* __restrict__ npos, double* __restrict__ dacc)
{
    const int b = blockIdx.y;
    const int p = blockIdx.x * 256 + threadIdx.x;
    const int tid = threadIdx.x;
    __shared__ float tr[OO * 5];
    if (tid < OO * 5) tr[tid] = targets[(size_t)b * OO * 5 + tid];
    __syncthreads();

    float ov = btov[(size_t)b * PP + p];
    int o = btidx[(size_t)b * PP + p];
    int conft = 0;
    if (ov >= 0.5f) conft = (int)(tr[o*5+4] + 1.0f);
    bool pos = conft > 0;

    const float* cr = conf + ((size_t)b * PP + p) * NC;
    float x[NC];
    float m = -1e30f;
#pragma unroll
    for (int c = 0; c < NC; ++c) { x[c] = cr[c]; m = fmaxf(m, x[c]); }
    float s = 0.0f, tl = 0.0f;
#pragma unroll
    for (int c = 0; c < NC; ++c) { s += expf(x[c] - m); if (c == conft) tl = x[c]; }
    float ce = (m + logf(s)) - tl;

    cemine[(size_t)b * PP + p] = pos ? 0.0f : ce;

    double l_l = 0.0, pce = 0.0; int np_ = 0;
    if (pos) {
        np_ = 1; pce = (double)ce;
        float mx1 = tr[o*5+0], my1 = tr[o*5+1], mx2 = tr[o*5+2], my2 = tr[o*5+3];
        float4 pr = *(const float4*)(priors + (size_t)p * 4);
        float lt0 = ((mx1 + mx2) * 0.5f - pr.x) / (0.1f * pr.z);
        float lt1 = ((my1 + my2) * 0.5f - pr.y) / (0.1f * pr.w);
        float lt2 = logf((mx2 - mx1) / pr.z) / 0.2f;
        float lt3 = logf((my2 - my1) / pr.w) / 0.2f;
        const float* lp = loc + ((size_t)b * PP + p) * 4;
        float lt[4] = {lt0, lt1, lt2, lt3};
#pragma unroll
        for (int i2 = 0; i2 < 4; ++i2) {
            float d = lp[i2] - lt[i2];
            float ad = fabsf(d);
            l_l += (double)(ad < 1.0f ? 0.5f * d * d : ad - 0.5f);
        }
    }

    __shared__ double rl[256], rc[256];
    __shared__ int rn[256];
    rl[tid] = l_l; rc[tid] = pce; rn[tid] = np_;
    __syncthreads();
    for (int s2 = 128; s2 > 0; s2 >>= 1) {
        if (tid < s2) { rl[tid] += rl[tid+s2]; rc[tid] += rc[tid+s2]; rn[tid] += rn[tid+s2]; }
        __syncthreads();
    }
    if (tid == 0) {
        atomicAdd(&dacc[b], rl[0]);
        atomicAdd(&dacc[BB + b], rc[0]);
        atomicAdd(&npos[b], rn[0]);
    }
}

static __device__ __forceinline__ u32 top16bits(float v) {
    // values are >= 0; map <=0 (incl. -0.0) to 0
    u32 u = __float_as_uint(v);
    return (v > 0.0f) ? u : 0u;
}

// Pass 1: histogram of top-16 float bits per batch, global atomics, 512 blocks.
__global__ __launch_bounds__(256) void hist16_kernel(
    const float* __restrict__ cemine, u32* __restrict__ hist)
{
    const int b = blockIdx.y;
    const float4* v4 = (const float4*)(cemine + (size_t)b * PP);
    u32* h = hist + (size_t)b * NBIN;
    int i0 = blockIdx.x * 512 + threadIdx.x;   // 16 blocks x 512 float4 = 8192 float4
#pragma unroll
    for (int r = 0; r < 2; ++r) {
        float4 f = v4[i0 + r * 256];
        atomicAdd(&h[top16bits(f.x) >> 16], 1u);
        atomicAdd(&h[top16bits(f.y) >> 16], 1u);
        atomicAdd(&h[top16bits(f.z) >> 16], 1u);
        atomicAdd(&h[top16bits(f.w) >> 16], 1u);
    }
}

// Find threshold bin T16 and residual count k2 (suffix-scan from top bin).
__global__ __launch_bounds__(256) void select16_kernel(
    const u32* __restrict__ hist, const int* __restrict__ npos,
    u32* __restrict__ selT, int* __restrict__ selK)
{
    const int b = blockIdx.x, tid = threadIdx.x;
    int k = npos[b] * 3; if (k > PP - 1) k = PP - 1;
    if (k <= 0) { if (tid == 0) { selT[b] = 0x10000u; selK[b] = 0; } return; }

    const u32* h = hist + (size_t)b * NBIN;
    const int base = tid * 256;
    u32 tot = 0;
    for (int j = 0; j < 256; ++j) tot += h[base + j];
    __shared__ u32 cnts[256];
    cnts[tid] = tot;
    __syncthreads();
    u32 above = 0;
    for (int t = tid + 1; t < 256; ++t) above += cnts[t];
    if (above < (u32)k && above + tot >= (u32)k) {
        u32 cum = above;
        for (int j = 255; j >= 0; --j) {
            u32 hv = h[base + j];
            if (cum + hv >= (u32)k) { selT[b] = (u32)(base + j); selK[b] = k - (int)cum; break; }
            cum += hv;
        }
    }
}

// Pass 2: sum of values strictly above the threshold bin (double atomics) +
// low-16-bit histogram of elements inside the threshold bin.
__global__ __launch_bounds__(256) void scan2_kernel(
    const float* __restrict__ cemine, const u32* __restrict__ selT,
    u32* __restrict__ hist2, double* __restrict__ dacc)
{
    const int b = blockIdx.y, tid = threadIdx.x;
    const u32 T16 = selT[b];
    const float4* v4 = (const float4*)(cemine + (size_t)b * PP);
    u32* h2 = hist2 + (size_t)b * NBIN;
    float4 f = v4[blockIdx.x * 256 + tid];    // 32 blocks x 256 float4
    double acc = 0.0;
    float vv[4] = {f.x, f.y, f.z, f.w};
#pragma unroll
    for (int c = 0; c < 4; ++c) {
        u32 u = top16bits(vv[c]);
        u32 hi = u >> 16;
        if (hi > T16) acc += (double)vv[c];
        else if (hi == T16) atomicAdd(&h2[u & 0xFFFFu], 1u);
    }
    __shared__ double red[256];
    red[tid] = acc;
    __syncthreads();
    for (int s2 = 128; s2 > 0; s2 >>= 1) {
        if (tid < s2) red[tid] += red[tid + s2];
        __syncthreads();
    }
    if (tid == 0 && red[0] != 0.0) atomicAdd(&dacc[2 * BB + b], red[0]);
}

// Final: exact within-bin top-k2 sum; values reconstructed as (T16<<16)|low16.
__global__ __launch_bounds__(256) void selfinal_kernel(
    const u32* __restrict__ hist2, const u32* __restrict__ selT,
    const int* __restrict__ selK, double* __restrict__ dacc)
{
    const int b = blockIdx.x, tid = threadIdx.x;
    const int k2 = selK[b];
    if (k2 <= 0) return;
    const u32 T16 = selT[b];
    const u32* h2 = hist2 + (size_t)b * NBIN;
    const int base = tid * 256;
    u32 tot = 0; double sv = 0.0;
    for (int j = 0; j < 256; ++j) {
        u32 hv = h2[base + j];
        if (hv) {
            tot += hv;
            sv += (double)hv * (double)__uint_as_float((T16 << 16) | (u32)(base + j));
        }
    }
    __shared__ u32 cnts[256];
    __shared__ double svs[256];
    cnts[tid] = tot; svs[tid] = sv;
    __syncthreads();
    u32 above = 0;
    for (int t = tid + 1; t < 256; ++t) above += cnts[t];
    if (above < (u32)k2 && above + tot >= (u32)k2) {
        double add = 0.0;
        for (int t = tid + 1; t < 256; ++t) add += svs[t];
        u32 cum = above;
        for (int j = 255; j >= 0; --j) {
            u32 hv = h2[base + j];
            double val = (double)__uint_as_float((T16 << 16) | (u32)(base + j));
            if (cum + hv >= (u32)k2) { add += (double)((u32)k2 - cum) * val; break; }
            cum += hv;
            add += (double)hv * val;
        }
        dacc[2 * BB + b] += add;   // one writer per b; sumAbove already there
    }
}

__global__ void finalize_kernel(const int* __restrict__ npos,
                                const double* __restrict__ dacc, float* __restrict__ out) {
    if (threadIdx.x == 0 && blockIdx.x == 0) {
        double N = 0.0, ll = 0.0, lc = 0.0;
        for (int b = 0; b < BB; ++b) {
            N += (double)npos[b];
            ll += dacc[b];
            lc += dacc[BB + b] + dacc[2 * BB + b];
        }
        out[0] = (float)(ll / N);
        out[1] = (float)(lc / N);
    }
}

extern "C" void kernel_launch(void* const* d_in, const int* in_sizes, int n_in,
                              void* d_out, int out_size, void* d_ws, size_t ws_size,
                              hipStream_t stream) {
    const float* loc     = (const float*)d_in[0];
    const float* conf    = (const float*)d_in[1];
    const float* priors  = (const float*)d_in[2];
    const float* targets = (const float*)d_in[3];
    char* ws = (char*)d_ws;
    u64*    keys  = (u64*)   (ws + OFF_KEYS);
    float*  btov  = (float*) (ws + OFF_BTOV);
    u8*     btidx = (u8*)    (ws + OFF_BTIDX);
    float*  cem   = (float*) (ws + OFF_CEM);
    int*    npos  = (int*)   (ws + OFF_NPOS);
    u32*    selT  = (u32*)   (ws + OFF_SELT);
    int*    selK  = (int*)   (ws + OFF_SELK);
    double* dacc  = (double*)(ws + OFF_DACC);
    u32*    hist  = (u32*)   (ws + OFF_HIST);
    u32*    hist2 = (u32*)   (ws + OFF_HIST2);
    float*  out   = (float*)d_out;

    hipMemsetAsync(hist, 0, 4ull * BB * NBIN * 2, stream);  // hist + hist2 contiguous
    init_kernel<<<7, 256, 0, stream>>>(keys, npos, dacc);
    dim3 g1(PP / 256, BB);
    match_kernel<<<g1, 256, 0, stream>>>(priors, targets, btov, btidx, keys);
    override_kernel<<<1, 32, 0, stream>>>(keys, btov, btidx);
    score_kernel<<<g1, 256, 0, stream>>>(loc, conf, priors, targets, btov, btidx, cem, npos, dacc);
    hist16_kernel<<<dim3(16, BB), 256, 0, stream>>>(cem, hist);
    select16_kernel<<<BB, 256, 0, stream>>>(hist, npos, selT, selK);
    scan2_kernel<<<dim3(32, BB), 256, 0, stream>>>(cem, selT, hist2, dacc);
    selfinal_kernel<<<BB, 256, 0, stream>>>(hist2, selT, selK, dacc);
    finalize_kernel<<<1, 64, 0, stream>>>(npos, dacc, out);
}

// Round 3
// 260.956 us; speedup vs baseline: 1.9599x; 1.2625x over previous
//
#include <hip/hip_runtime.h>
#include <math.h>

#define BB 32
#define PP 32768
#define OO 50
#define NC 21
#define NBIN 65536
#define MPT 4            // priors per thread in match_kernel

typedef unsigned long long u64;
typedef unsigned int u32;
typedef unsigned char u8;

// workspace layout (all offsets 128B-aligned)
static constexpr size_t OFF_KEYS  = 0;                           // u64[BB*OO]
static constexpr size_t OFF_BTOV  = 16384;                       // float[BB*PP]
static constexpr size_t OFF_BTIDX = OFF_BTOV  + 4ull*BB*PP;      // u8[BB*PP]
static constexpr size_t OFF_CEM   = OFF_BTIDX + 1ull*BB*PP;      // float[BB*PP]
static constexpr size_t OFF_NPOS  = OFF_CEM   + 4ull*BB*PP;      // int[BB]
static constexpr size_t OFF_SELT  = OFF_NPOS  + 128;             // u32[BB] threshold top16 bin
static constexpr size_t OFF_SELK  = OFF_SELT  + 128;             // int[BB] residual k within bin
static constexpr size_t OFF_DACC  = OFF_SELK  + 128;             // double[3*BB]: lossl, posce, topk
static constexpr size_t OFF_HIST  = OFF_DACC  + 8ull*3*BB + 64;  // u32[BB*NBIN]
static constexpr size_t OFF_HIST2 = OFF_HIST  + 4ull*BB*NBIN;    // u32[BB*NBIN]

__global__ void init_kernel(u64* __restrict__ keys, int* __restrict__ npos,
                            double* __restrict__ dacc) {
    int i = blockIdx.x * 256 + threadIdx.x;
    if (i < BB * OO) keys[i] = 0ull;
    if (i < BB) npos[i] = 0;
    if (i < 3 * BB) dacc[i] = 0.0;
}

// Per (b, 4 priors): IoU against all 50 truths. Per-prior best truth is
// thread-local (strict > keeps first max over o). Per-truth best prior:
// float-only 64-lane butterfly max, then 4 ordered ballots pick the smallest
// (slot, lane) == smallest p (numpy argmax first-occurrence), packed into a
// u64 key (value_bits<<32 | ~p) merged across waves/blocks via atomicMax.
__global__ __launch_bounds__(256) void match_kernel(
    const float* __restrict__ priors, const float* __restrict__ targets,
    float* __restrict__ btov, u8* __restrict__ btidx, u64* __restrict__ keys)
{
#pragma clang fp contract(off)
    const int b = blockIdx.y;
    const int tid = threadIdx.x;
    const int lane = tid & 63, wid = tid >> 6;
    const int wbase = blockIdx.x * (256 * MPT) + wid * (64 * MPT);  // wave covers 256 priors

    __shared__ float tr[OO * 5];
    __shared__ u64 wkeys[4][OO];
    if (tid < OO * 5) tr[tid] = targets[(size_t)b * OO * 5 + tid];
    __syncthreads();

    float px1[MPT], py1[MPT], px2[MPT], py2[MPT], area_p[MPT];
#pragma unroll
    for (int s = 0; s < MPT; ++s) {
        int p = wbase + s * 64 + lane;
        float4 pr = *(const float4*)(priors + (size_t)p * 4);
        px1[s] = pr.x - pr.z * 0.5f; py1[s] = pr.y - pr.w * 0.5f;
        px2[s] = pr.x + pr.z * 0.5f; py2[s] = pr.y + pr.w * 0.5f;
        area_p[s] = (px2[s] - px1[s]) * (py2[s] - py1[s]);
    }

    float bestv[MPT]; int besto[MPT];
#pragma unroll
    for (int s = 0; s < MPT; ++s) { bestv[s] = -1.0f; besto[s] = 0; }

    for (int o = 0; o < OO; ++o) {
        float tx1 = tr[o*5+0], ty1 = tr[o*5+1], tx2 = tr[o*5+2], ty2 = tr[o*5+3];
        float area_t = (tx2 - tx1) * (ty2 - ty1);
        float iou[MPT];
#pragma unroll
        for (int s = 0; s < MPT; ++s) {
            float ix1 = fmaxf(tx1, px1[s]), iy1 = fmaxf(ty1, py1[s]);
            float ix2 = fminf(tx2, px2[s]), iy2 = fminf(ty2, py2[s]);
            float dx = fmaxf(ix2 - ix1, 0.0f), dy = fmaxf(iy2 - iy1, 0.0f);
            float inter = dx * dy;
            iou[s] = inter / ((area_t + area_p[s]) - inter);
            if (iou[s] > bestv[s]) { bestv[s] = iou[s]; besto[s] = o; }
        }
        // wave max of all 4 slots (float-only butterfly)
        float mv = fmaxf(fmaxf(iou[0], iou[1]), fmaxf(iou[2], iou[3]));
        for (int m = 1; m < 64; m <<= 1)
            mv = fmaxf(mv, __shfl_xor(mv, m, 64));
        // winner = smallest slot, then smallest lane  => smallest p
        u64 b0 = __ballot(iou[0] == mv);
        u64 b1 = __ballot(iou[1] == mv);
        u64 b2 = __ballot(iou[2] == mv);
        u64 b3 = __ballot(iou[3] == mv);
        if (lane == 0) {
            int s, l;
            if      (b0) { s = 0; l = __ffsll(b0) - 1; }
            else if (b1) { s = 1; l = __ffsll(b1) - 1; }
            else if (b2) { s = 2; l = __ffsll(b2) - 1; }
            else if (b3) { s = 3; l = __ffsll(b3) - 1; }
            else         { s = 0; l = 0; }
            u32 wp = (u32)(wbase + s * 64 + l);
            wkeys[wid][o] = ((u64)__float_as_uint(mv) << 32) | (u64)(0xFFFFFFFFu - wp);
        }
    }
#pragma unroll
    for (int s = 0; s < MPT; ++s) {
        int p = wbase + s * 64 + lane;
        btov[(size_t)b * PP + p] = bestv[s];
        btidx[(size_t)b * PP + p] = (u8)besto[s];
    }
    __syncthreads();
    if (tid < OO) {
        u64 k0 = wkeys[0][tid];
        for (int w = 1; w < 4; ++w) { u64 kw = wkeys[w][tid]; if (kw > k0) k0 = kw; }
        atomicMax(&keys[b * OO + tid], k0);
    }
}

// Sequential per batch (last-wins scatter, matches numpy fancy assignment).
__global__ void override_kernel(const u64* __restrict__ keys,
                                float* __restrict__ btov, u8* __restrict__ btidx) {
    int b = threadIdx.x;
    if (b >= BB) return;
    for (int o = 0; o < OO; ++o) {
        u64 key = keys[b * OO + o];
        u32 p = 0xFFFFFFFFu - (u32)(key & 0xFFFFFFFFull);
        btov[(size_t)b * PP + p] = 2.0f;
        btidx[(size_t)b * PP + p] = (u8)o;
    }
}

__global__ __launch_bounds__(256) void score_kernel(
    const float* __restrict__ loc, const float* __restrict__ conf,
    const float* __restrict__ priors, const float* __restrict__ targets,
    const float* __restrict__ btov, const u8* __restrict__ btidx,
    float* __restrict__ cemine, int* __restrict__ npos, double* __restrict__ dacc)
{
    const int b = blockIdx.y;
    const int p0 = blockIdx.x * 256;
    const int p = p0 + threadIdx.x;
    const int tid = threadIdx.x;
    __shared__ float tr[OO * 5];
    __shared__ float scf[256 * NC];        // conf slab; reused for reductions
    if (tid < OO * 5) tr[tid] = targets[(size_t)b * OO * 5 + tid];

    // coalesced conf load: 21 fully-coalesced dword rounds -> LDS row-major
    {
        const float* cb = conf + ((size_t)b * PP + p0) * NC;
#pragma unroll
        for (int j = 0; j < NC; ++j) scf[j * 256 + tid] = cb[j * 256 + tid];
    }
    __syncthreads();

    float ov = btov[(size_t)b * PP + p];
    int o = btidx[(size_t)b * PP + p];
    int conft = 0;
    if (ov >= 0.5f) conft = (int)(tr[o*5+4] + 1.0f);
    bool pos = conft > 0;

    const float* row = scf + tid * NC;     // stride 21 (odd) -> 2-way bank alias, free
    float m = -1e30f;
#pragma unroll
    for (int c = 0; c < NC; ++c) m = fmaxf(m, row[c]);
    float s = 0.0f, tl = 0.0f;
#pragma unroll
    for (int c = 0; c < NC; ++c) { s += expf(row[c] - m); if (c == conft) tl = row[c]; }
    float ce = (m + logf(s)) - tl;

    cemine[(size_t)b * PP + p] = pos ? 0.0f : ce;

    double l_l = 0.0, pce = 0.0; int np_ = 0;
    if (pos) {
        np_ = 1; pce = (double)ce;
        float mx1 = tr[o*5+0], my1 = tr[o*5+1], mx2 = tr[o*5+2], my2 = tr[o*5+3];
        float4 pr = *(const float4*)(priors + (size_t)p * 4);
        float lt0 = ((mx1 + mx2) * 0.5f - pr.x) / (0.1f * pr.z);
        float lt1 = ((my1 + my2) * 0.5f - pr.y) / (0.1f * pr.w);
        float lt2 = logf((mx2 - mx1) / pr.z) / 0.2f;
        float lt3 = logf((my2 - my1) / pr.w) / 0.2f;
        const float* lp = loc + ((size_t)b * PP + p) * 4;
        float lt[4] = {lt0, lt1, lt2, lt3};
#pragma unroll
        for (int i2 = 0; i2 < 4; ++i2) {
            float d = lp[i2] - lt[i2];
            float ad = fabsf(d);
            l_l += (double)(ad < 1.0f ? 0.5f * d * d : ad - 0.5f);
        }
    }

    __syncthreads();                       // done reading scf; reuse for reductions
    double* rl = (double*)scf;             // 256 doubles
    double* rc = rl + 256;                 // 256 doubles
    int*    rn = (int*)(rc + 256);         // 256 ints
    rl[tid] = l_l; rc[tid] = pce; rn[tid] = np_;
    __syncthreads();
    for (int s2 = 128; s2 > 0; s2 >>= 1) {
        if (tid < s2) { rl[tid] += rl[tid+s2]; rc[tid] += rc[tid+s2]; rn[tid] += rn[tid+s2]; }
        __syncthreads();
    }
    if (tid == 0) {
        atomicAdd(&dacc[b], rl[0]);
        atomicAdd(&dacc[BB + b], rc[0]);
        atomicAdd(&npos[b], rn[0]);
    }
}

static __device__ __forceinline__ u32 top16bits(float v) {
    u32 u = __float_as_uint(v);
    return (v > 0.0f) ? u : 0u;
}

// Pass 1: histogram of top-16 float bits per batch, global atomics.
__global__ __launch_bounds__(256) void hist16_kernel(
    const float* __restrict__ cemine, u32* __restrict__ hist)
{
    const int b = blockIdx.y;
    const float4* v4 = (const float4*)(cemine + (size_t)b * PP);
    u32* h = hist + (size_t)b * NBIN;
    int i0 = blockIdx.x * 512 + threadIdx.x;
#pragma unroll
    for (int r = 0; r < 2; ++r) {
        float4 f = v4[i0 + r * 256];
        atomicAdd(&h[top16bits(f.x) >> 16], 1u);
        atomicAdd(&h[top16bits(f.y) >> 16], 1u);
        atomicAdd(&h[top16bits(f.z) >> 16], 1u);
        atomicAdd(&h[top16bits(f.w) >> 16], 1u);
    }
}

// Find threshold bin T16 and residual count k2 (suffix-scan from top bin).
__global__ __launch_bounds__(256) void select16_kernel(
    const u32* __restrict__ hist, const int* __restrict__ npos,
    u32* __restrict__ selT, int* __restrict__ selK)
{
    const int b = blockIdx.x, tid = threadIdx.x;
    int k = npos[b] * 3; if (k > PP - 1) k = PP - 1;
    if (k <= 0) { if (tid == 0) { selT[b] = 0x10000u; selK[b] = 0; } return; }

    const u32* h = hist + (size_t)b * NBIN;
    const int base = tid * 256;
    u32 tot = 0;
    for (int j = 0; j < 256; ++j) tot += h[base + j];
    __shared__ u32 cnts[256];
    cnts[tid] = tot;
    __syncthreads();
    u32 above = 0;
    for (int t = tid + 1; t < 256; ++t) above += cnts[t];
    if (above < (u32)k && above + tot >= (u32)k) {
        u32 cum = above;
        for (int j = 255; j >= 0; --j) {
            u32 hv = h[base + j];
            if (cum + hv >= (u32)k) { selT[b] = (u32)(base + j); selK[b] = k - (int)cum; break; }
            cum += hv;
        }
    }
}

// Pass 2: sum above threshold bin (double atomics) + low-16 histogram inside it.
__global__ __launch_bounds__(256) void scan2_kernel(
    const float* __restrict__ cemine, const u32* __restrict__ selT,
    u32* __restrict__ hist2, double* __restrict__ dacc)
{
    const int b = blockIdx.y, tid = threadIdx.x;
    const u32 T16 = selT[b];
    const float4* v4 = (const float4*)(cemine + (size_t)b * PP);
    u32* h2 = hist2 + (size_t)b * NBIN;
    float4 f = v4[blockIdx.x * 256 + tid];
    double acc = 0.0;
    float vv[4] = {f.x, f.y, f.z, f.w};
#pragma unroll
    for (int c = 0; c < 4; ++c) {
        u32 u = top16bits(vv[c]);
        u32 hi = u >> 16;
        if (hi > T16) acc += (double)vv[c];
        else if (hi == T16) atomicAdd(&h2[u & 0xFFFFu], 1u);
    }
    __shared__ double red[256];
    red[tid] = acc;
    __syncthreads();
    for (int s2 = 128; s2 > 0; s2 >>= 1) {
        if (tid < s2) red[tid] += red[tid + s2];
        __syncthreads();
    }
    if (tid == 0 && red[0] != 0.0) atomicAdd(&dacc[2 * BB + b], red[0]);
}

// Final: exact within-bin top-k2 sum; values reconstructed as (T16<<16)|low16.
__global__ __launch_bounds__(256) void selfinal_kernel(
    const u32* __restrict__ hist2, const u32* __restrict__ selT,
    const int* __restrict__ selK, double* __restrict__ dacc)
{
    const int b = blockIdx.x, tid = threadIdx.x;
    const int k2 = selK[b];
    if (k2 <= 0) return;
    const u32 T16 = selT[b];
    const u32* h2 = hist2 + (size_t)b * NBIN;
    const int base = tid * 256;
    u32 tot = 0; double sv = 0.0;
    for (int j = 0; j < 256; ++j) {
        u32 hv = h2[base + j];
        if (hv) {
            tot += hv;
            sv += (double)hv * (double)__uint_as_float((T16 << 16) | (u32)(base + j));
        }
    }
    __shared__ u32 cnts[256];
    __shared__ double svs[256];
    cnts[tid] = tot; svs[tid] = sv;
    __syncthreads();
    u32 above = 0;
    for (int t = tid + 1; t < 256; ++t) above += cnts[t];
    if (above < (u32)k2 && above + tot >= (u32)k2) {
        double add = 0.0;
        for (int t = tid + 1; t < 256; ++t) add += svs[t];
        u32 cum = above;
        for (int j = 255; j >= 0; --j) {
            u32 hv = h2[base + j];
            double val = (double)__uint_as_float((T16 << 16) | (u32)(base + j));
            if (cum + hv >= (u32)k2) { add += (double)((u32)k2 - cum) * val; break; }
            cum += hv;
            add += (double)hv * val;
        }
        dacc[2 * BB + b] += add;
    }
}

__global__ void finalize_kernel(const int* __restrict__ npos,
                                const double* __restrict__ dacc, float* __restrict__ out) {
    if (threadIdx.x == 0 && blockIdx.x == 0) {
        double N = 0.0, ll = 0.0, lc = 0.0;
        for (int b = 0; b < BB; ++b) {
            N += (double)npos[b];
            ll += dacc[b];
            lc += dacc[BB + b] + dacc[2 * BB + b];
        }
        out[0] = (float)(ll / N);
        out[1] = (float)(lc / N);
    }
}

extern "C" void kernel_launch(void* const* d_in, const int* in_sizes, int n_in,
                              void* d_out, int out_size, void* d_ws, size_t ws_size,
                              hipStream_t stream) {
    const float* loc     = (const float*)d_in[0];
    const float* conf    = (const float*)d_in[1];
    const float* priors  = (const float*)d_in[2];
    const float* targets = (const float*)d_in[3];
    char* ws = (char*)d_ws;
    u64*    keys  = (u64*)   (ws + OFF_KEYS);
    float*  btov  = (float*) (ws + OFF_BTOV);
    u8*     btidx = (u8*)    (ws + OFF_BTIDX);
    float*  cem   = (float*) (ws + OFF_CEM);
    int*    npos  = (int*)   (ws + OFF_NPOS);
    u32*    selT  = (u32*)   (ws + OFF_SELT);
    int*    selK  = (int*)   (ws + OFF_SELK);
    double* dacc  = (double*)(ws + OFF_DACC);
    u32*    hist  = (u32*)   (ws + OFF_HIST);
    u32*    hist2 = (u32*)   (ws + OFF_HIST2);
    float*  out   = (float*)d_out;

    hipMemsetAsync(hist, 0, 4ull * BB * NBIN * 2, stream);  // hist + hist2 contiguous
    init_kernel<<<7, 256, 0, stream>>>(keys, npos, dacc);
    match_kernel<<<dim3(PP / (256 * MPT), BB), 256, 0, stream>>>(priors, targets, btov, btidx, keys);
    override_kernel<<<1, 32, 0, stream>>>(keys, btov, btidx);
    score_kernel<<<dim3(PP / 256, BB), 256, 0, stream>>>(loc, conf, priors, targets, btov, btidx, cem, npos, dacc);
    hist16_kernel<<<dim3(16, BB), 256, 0, stream>>>(cem, hist);
    select16_kernel<<<BB, 256, 0, stream>>>(hist, npos, selT, selK);
    scan2_kernel<<<dim3(32, BB), 256, 0, stream>>>(cem, selT, hist2, dacc);
    selfinal_kernel<<<BB, 256, 0, stream>>>(hist2, selT, selK, dacc);
    finalize_kernel<<<1, 64, 0, stream>>>(npos, dacc, out);
}